// Round 6
// baseline (367.980 us; speedup 1.0000x reference)
//
#include <hip/hip_runtime.h>
#include <math.h>

#define NBATCH 16
#define CH 64
#define HID 16

#define SEG_BLOCKS  2048
#define SEG_THREADS 256
#define RED_BLOCKS  64
#define RED_CHUNK   (SEG_BLOCKS / RED_BLOCKS)

__device__ __forceinline__ void bnd_search(const int* __restrict__ bidx,
                                           int n_rows, int* bnd, int tid) {
    if (tid <= NBATCH) {
        if (tid == NBATCH) {
            bnd[NBATCH] = n_rows;
        } else {
            int lo = 0, hi = n_rows;          // first idx with bidx[idx] >= tid
            while (lo < hi) {
                const int mid = (lo + hi) >> 1;
                if (bidx[mid] < tid) lo = mid + 1; else hi = mid;
            }
            bnd[tid] = lo;
        }
    }
}

// ---------------------------------------------------------------------------
// Pass 1: per-block partial segment sums over a CONTIGUOUS slab.
// Slab split at segment boundaries (from bnd, no bidx reads in hot loop);
// per-segment inner loop is branch-free, 4x unrolled (4 x 16B loads in
// flight). Flush to LDS once per (thread,segment).
// ---------------------------------------------------------------------------
__global__ __launch_bounds__(SEG_THREADS) void seg_partial_kernel(
    const float4* __restrict__ feats4,   // [N*16]
    const int*    __restrict__ bidx,     // [N] sorted
    float*        __restrict__ partials, // [SEG_BLOCKS * NBATCH*CH]
    int n_rows)
{
    __shared__ float lds[NBATCH * CH];
    __shared__ int   bnd[NBATCH + 1];
    const int tid = threadIdx.x;

    for (int j = tid; j < NBATCH * CH; j += SEG_THREADS) lds[j] = 0.f;
    bnd_search(bidx, n_rows, bnd, tid);
    __syncthreads();

    const int n4   = n_rows * 16;
    const int slab = (n4 + SEG_BLOCKS - 1) / SEG_BLOCKS;
    int lo = blockIdx.x * slab;
    const int hi = min(lo + slab, n4);

    int b = 0;
    while (b < NBATCH - 1 && lo >= bnd[b + 1] * 16) ++b;

    while (lo < hi) {
        const int send = min(hi, bnd[b + 1] * 16);
        if (send > lo) {
            float4 acc = make_float4(0.f, 0.f, 0.f, 0.f);
            int i = lo + tid;
            for (; i + 3 * SEG_THREADS < send; i += 4 * SEG_THREADS) {
                const float4 v0 = feats4[i];
                const float4 v1 = feats4[i +     SEG_THREADS];
                const float4 v2 = feats4[i + 2 * SEG_THREADS];
                const float4 v3 = feats4[i + 3 * SEG_THREADS];
                acc.x += v0.x + v1.x + v2.x + v3.x;
                acc.y += v0.y + v1.y + v2.y + v3.y;
                acc.z += v0.z + v1.z + v2.z + v3.z;
                acc.w += v0.w + v1.w + v2.w + v3.w;
            }
            for (; i < send; i += SEG_THREADS) {
                const float4 v = feats4[i];
                acc.x += v.x; acc.y += v.y; acc.z += v.z; acc.w += v.w;
            }
            const int q = (lo + tid) & 15;       // fixed within this segment
            float* s = &lds[b * CH + q * 4];
            atomicAdd(s + 0, acc.x); atomicAdd(s + 1, acc.y);
            atomicAdd(s + 2, acc.z); atomicAdd(s + 3, acc.w);
        }
        lo = send > lo ? send : lo;
        if (lo >= hi) break;
        ++b;
    }
    __syncthreads();

    float4*       p4 = (float4*)(partials + (size_t)blockIdx.x * (NBATCH * CH));
    const float4* l4 = (const float4*)lds;
    p4[tid] = l4[tid];                           // 256 float4 == 1024 floats
}

// ---------------------------------------------------------------------------
// Pass 2: reduce partials -> sums. 64 blocks; 64 atomics per address total.
// ---------------------------------------------------------------------------
__global__ __launch_bounds__(256) void reduce_kernel(
    const float4* __restrict__ partials4,  // [SEG_BLOCKS*256]
    float*        __restrict__ sums)       // [NBATCH*CH]
{
    const int tid  = threadIdx.x;          // 0..255
    const int base = blockIdx.x * RED_CHUNK;
    float4 acc = make_float4(0.f, 0.f, 0.f, 0.f);
    #pragma unroll 8
    for (int k = 0; k < RED_CHUNK; ++k) {
        const float4 v = partials4[(size_t)(base + k) * 256 + tid];
        acc.x += v.x; acc.y += v.y; acc.z += v.z; acc.w += v.w;
    }
    float* s = &sums[tid * 4];
    atomicAdd(s + 0, acc.x); atomicAdd(s + 1, acc.y);
    atomicAdd(s + 2, acc.z); atomicAdd(s + 3, acc.w);
}

// ---------------------------------------------------------------------------
// Pass 3: tiny SE MLP, one block; counts via binary search on sorted bidx.
// ---------------------------------------------------------------------------
__global__ __launch_bounds__(1024) void mlp_kernel(
    const float* __restrict__ sums,
    const int*   __restrict__ bidx,
    int n_rows,
    const float* __restrict__ W1,
    const float* __restrict__ b1,
    const float* __restrict__ W2,
    const float* __restrict__ b2,
    float*       __restrict__ gate)
{
    __shared__ float mean_s[NBATCH * CH];
    __shared__ float h_s[NBATCH * HID];
    __shared__ int   bnd[NBATCH + 1];
    const int tid = threadIdx.x;

    bnd_search(bidx, n_rows, bnd, tid);
    __syncthreads();

    {
        const int b = tid >> 6;
        const float cnt = (float)(bnd[b + 1] - bnd[b]);
        mean_s[tid] = sums[tid] / fmaxf(cnt, 1.0f);
    }
    __syncthreads();

    if (tid < NBATCH * HID) {
        const int b = tid >> 4, j = tid & 15;
        float a = b1[j];
        #pragma unroll 8
        for (int c = 0; c < CH; ++c) a += mean_s[b * CH + c] * W1[c * HID + j];
        h_s[tid] = fmaxf(a, 0.f);
    }
    __syncthreads();

    {
        const int b = tid >> 6, ch = tid & 63;
        float a = b2[ch];
        #pragma unroll
        for (int j = 0; j < HID; ++j) a += h_s[b * HID + j] * W2[j * CH + ch];
        gate[tid] = 1.0f / (1.0f + expf(-a));
    }
}

// ---------------------------------------------------------------------------
// Pass 4: apply. Same slab structure; gate in a register per segment;
// branch-free 4x-unrolled load/mul/store. PLAIN float4 stores (A/B vs R5's
// nontemporal: fill kernel proves plain stores sustain 6.8 TB/s).
// ---------------------------------------------------------------------------
__global__ __launch_bounds__(SEG_THREADS) void apply_kernel(
    const float4* __restrict__ feats4,
    const int*    __restrict__ bidx,
    const float4* __restrict__ gate4,   // [NBATCH*16]
    float4*       __restrict__ out4,
    int n_rows)
{
    __shared__ float gate_s[NBATCH * CH];
    __shared__ int   bnd[NBATCH + 1];
    const int tid = threadIdx.x;

    ((float4*)gate_s)[tid] = gate4[tid];         // 256 float4 == whole gate
    bnd_search(bidx, n_rows, bnd, tid);
    __syncthreads();
    const float4* gs4 = (const float4*)gate_s;

    const int n4   = n_rows * 16;
    const int slab = (n4 + SEG_BLOCKS - 1) / SEG_BLOCKS;
    int lo = blockIdx.x * slab;
    const int hi = min(lo + slab, n4);

    int b = 0;
    while (b < NBATCH - 1 && lo >= bnd[b + 1] * 16) ++b;

    while (lo < hi) {
        const int send = min(hi, bnd[b + 1] * 16);
        if (send > lo) {
            const int q = (lo + tid) & 15;
            const float4 g = gs4[b * 16 + q];
            int i = lo + tid;
            for (; i + 3 * SEG_THREADS < send; i += 4 * SEG_THREADS) {
                const float4 v0 = feats4[i];
                const float4 v1 = feats4[i +     SEG_THREADS];
                const float4 v2 = feats4[i + 2 * SEG_THREADS];
                const float4 v3 = feats4[i + 3 * SEG_THREADS];
                out4[i]                   = make_float4(v0.x*g.x, v0.y*g.y, v0.z*g.z, v0.w*g.w);
                out4[i +     SEG_THREADS] = make_float4(v1.x*g.x, v1.y*g.y, v1.z*g.z, v1.w*g.w);
                out4[i + 2 * SEG_THREADS] = make_float4(v2.x*g.x, v2.y*g.y, v2.z*g.z, v2.w*g.w);
                out4[i + 3 * SEG_THREADS] = make_float4(v3.x*g.x, v3.y*g.y, v3.z*g.z, v3.w*g.w);
            }
            for (; i < send; i += SEG_THREADS) {
                const float4 v = feats4[i];
                out4[i] = make_float4(v.x*g.x, v.y*g.y, v.z*g.z, v.w*g.w);
            }
        }
        lo = send > lo ? send : lo;
        if (lo >= hi) break;
        ++b;
    }
}

extern "C" void kernel_launch(void* const* d_in, const int* in_sizes, int n_in,
                              void* d_out, int out_size, void* d_ws, size_t ws_size,
                              hipStream_t stream) {
    const float4* feats4 = (const float4*)d_in[0];
    const int*    bidx   = (const int*)d_in[1];
    const float*  W1     = (const float*)d_in[2];
    const float*  b1     = (const float*)d_in[3];
    const float*  W2     = (const float*)d_in[4];
    const float*  b2     = (const float*)d_in[5];
    float4* out4 = (float4*)d_out;
    const int n_rows = in_sizes[1];

    // ws layout: sums[1024] | gate[1024] | partials[SEG_BLOCKS*1024]
    float* sums = (float*)d_ws;
    float* gate = sums + NBATCH * CH;
    const size_t need = (size_t)(2 * NBATCH * CH + SEG_BLOCKS * NBATCH * CH) * sizeof(float);
    // fallback: stash partials in d_out (read by reduce_kernel strictly
    // before apply_kernel overwrites d_out — stream-ordered)
    float* partials = (ws_size >= need) ? (gate + NBATCH * CH) : (float*)d_out;

    (void)hipMemsetAsync(sums, 0, NBATCH * CH * sizeof(float), stream);

    seg_partial_kernel<<<SEG_BLOCKS, SEG_THREADS, 0, stream>>>(
        feats4, bidx, partials, n_rows);

    reduce_kernel<<<RED_BLOCKS, 256, 0, stream>>>(
        (const float4*)partials, sums);

    mlp_kernel<<<1, 1024, 0, stream>>>(
        sums, bidx, n_rows, W1, b1, W2, b2, gate);

    apply_kernel<<<SEG_BLOCKS, SEG_THREADS, 0, stream>>>(
        feats4, bidx, (const float4*)gate, out4, n_rows);
}

// Round 7
// 331.134 us; speedup vs baseline: 1.1113x; 1.1113x over previous
//
#include <hip/hip_runtime.h>
#include <math.h>

#define NBATCH 16
#define CH 64
#define HID 16

#define SEG_BLOCKS  2048
#define SEG_THREADS 256
#define RED_BLOCKS  64
#define RED_CHUNK   (SEG_BLOCKS / RED_BLOCKS)

__device__ __forceinline__ void bnd_search(const int* __restrict__ bidx,
                                           int n_rows, int* bnd, int tid) {
    if (tid <= NBATCH) {
        if (tid == NBATCH) {
            bnd[NBATCH] = n_rows;
        } else {
            int lo = 0, hi = n_rows;          // first idx with bidx[idx] >= tid
            while (lo < hi) {
                const int mid = (lo + hi) >> 1;
                if (bidx[mid] < tid) lo = mid + 1; else hi = mid;
            }
            bnd[tid] = lo;
        }
    }
}

// ---------------------------------------------------------------------------
// Pass 1: per-block partial segment sums over a CONTIGUOUS slab.
// Slab split at segment boundaries (from bnd, no bidx reads in hot loop);
// per-segment inner loop is branch-free, 4x unrolled. Believed ~85 us
// (read roofline) from R5/R6 residual analysis. UNCHANGED from R6.
// ---------------------------------------------------------------------------
__global__ __launch_bounds__(SEG_THREADS) void seg_partial_kernel(
    const float4* __restrict__ feats4,   // [N*16]
    const int*    __restrict__ bidx,     // [N] sorted
    float*        __restrict__ partials, // [SEG_BLOCKS * NBATCH*CH]
    int n_rows)
{
    __shared__ float lds[NBATCH * CH];
    __shared__ int   bnd[NBATCH + 1];
    const int tid = threadIdx.x;

    for (int j = tid; j < NBATCH * CH; j += SEG_THREADS) lds[j] = 0.f;
    bnd_search(bidx, n_rows, bnd, tid);
    __syncthreads();

    const int n4   = n_rows * 16;
    const int slab = (n4 + SEG_BLOCKS - 1) / SEG_BLOCKS;
    int lo = blockIdx.x * slab;
    const int hi = min(lo + slab, n4);

    int b = 0;
    while (b < NBATCH - 1 && lo >= bnd[b + 1] * 16) ++b;

    while (lo < hi) {
        const int send = min(hi, bnd[b + 1] * 16);
        if (send > lo) {
            float4 acc = make_float4(0.f, 0.f, 0.f, 0.f);
            int i = lo + tid;
            for (; i + 3 * SEG_THREADS < send; i += 4 * SEG_THREADS) {
                const float4 v0 = feats4[i];
                const float4 v1 = feats4[i +     SEG_THREADS];
                const float4 v2 = feats4[i + 2 * SEG_THREADS];
                const float4 v3 = feats4[i + 3 * SEG_THREADS];
                acc.x += v0.x + v1.x + v2.x + v3.x;
                acc.y += v0.y + v1.y + v2.y + v3.y;
                acc.z += v0.z + v1.z + v2.z + v3.z;
                acc.w += v0.w + v1.w + v2.w + v3.w;
            }
            for (; i < send; i += SEG_THREADS) {
                const float4 v = feats4[i];
                acc.x += v.x; acc.y += v.y; acc.z += v.z; acc.w += v.w;
            }
            const int q = (lo + tid) & 15;       // fixed within this segment
            float* s = &lds[b * CH + q * 4];
            atomicAdd(s + 0, acc.x); atomicAdd(s + 1, acc.y);
            atomicAdd(s + 2, acc.z); atomicAdd(s + 3, acc.w);
        }
        lo = send > lo ? send : lo;
        if (lo >= hi) break;
        ++b;
    }
    __syncthreads();

    float4*       p4 = (float4*)(partials + (size_t)blockIdx.x * (NBATCH * CH));
    const float4* l4 = (const float4*)lds;
    p4[tid] = l4[tid];                           // 256 float4 == 1024 floats
}

// ---------------------------------------------------------------------------
// Pass 2: reduce partials -> sums.
// ---------------------------------------------------------------------------
__global__ __launch_bounds__(256) void reduce_kernel(
    const float4* __restrict__ partials4,  // [SEG_BLOCKS*256]
    float*        __restrict__ sums)       // [NBATCH*CH]
{
    const int tid  = threadIdx.x;          // 0..255
    const int base = blockIdx.x * RED_CHUNK;
    float4 acc = make_float4(0.f, 0.f, 0.f, 0.f);
    #pragma unroll 8
    for (int k = 0; k < RED_CHUNK; ++k) {
        const float4 v = partials4[(size_t)(base + k) * 256 + tid];
        acc.x += v.x; acc.y += v.y; acc.z += v.z; acc.w += v.w;
    }
    float* s = &sums[tid * 4];
    atomicAdd(s + 0, acc.x); atomicAdd(s + 1, acc.y);
    atomicAdd(s + 2, acc.z); atomicAdd(s + 3, acc.w);
}

// ---------------------------------------------------------------------------
// Pass 3: tiny SE MLP, one block; counts via binary search on sorted bidx.
// ---------------------------------------------------------------------------
__global__ __launch_bounds__(1024) void mlp_kernel(
    const float* __restrict__ sums,
    const int*   __restrict__ bidx,
    int n_rows,
    const float* __restrict__ W1,
    const float* __restrict__ b1,
    const float* __restrict__ W2,
    const float* __restrict__ b2,
    float*       __restrict__ gate)
{
    __shared__ float mean_s[NBATCH * CH];
    __shared__ float h_s[NBATCH * HID];
    __shared__ int   bnd[NBATCH + 1];
    const int tid = threadIdx.x;

    bnd_search(bidx, n_rows, bnd, tid);
    __syncthreads();

    {
        const int b = tid >> 6;
        const float cnt = (float)(bnd[b + 1] - bnd[b]);
        mean_s[tid] = sums[tid] / fmaxf(cnt, 1.0f);
    }
    __syncthreads();

    if (tid < NBATCH * HID) {
        const int b = tid >> 4, j = tid & 15;
        float a = b1[j];
        #pragma unroll 8
        for (int c = 0; c < CH; ++c) a += mean_s[b * CH + c] * W1[c * HID + j];
        h_s[tid] = fmaxf(a, 0.f);
    }
    __syncthreads();

    {
        const int b = tid >> 6, ch = tid & 63;
        float a = b2[ch];
        #pragma unroll
        for (int j = 0; j < HID; ++j) a += h_s[b * HID + j] * W2[j * CH + ch];
        gate[tid] = 1.0f / (1.0f + expf(-a));
    }
}

// ---------------------------------------------------------------------------
// Pass 4: apply — EXACT R1 structure (measured ~125 us residual): simple
// grid-stride, per-row bidx read (L1-amortized over 16 threads), gate from
// global (L1-resident 4 KB), plain float4 stores. Do not touch.
// ---------------------------------------------------------------------------
__global__ __launch_bounds__(256) void apply_kernel(
    const float4* __restrict__ feats4,
    const int*    __restrict__ bidx,
    const float4* __restrict__ gate4,   // [NBATCH*16]
    float4*       __restrict__ out4,
    int n4)
{
    const int stride = gridDim.x * blockDim.x;
    for (int i = blockIdx.x * blockDim.x + threadIdx.x; i < n4; i += stride) {
        const int row = i >> 4;
        const int q   = i & 15;
        const int b   = bidx[row];
        const float4 v = feats4[i];
        const float4 g = gate4[b * 16 + q];
        out4[i] = make_float4(v.x * g.x, v.y * g.y, v.z * g.z, v.w * g.w);
    }
}

extern "C" void kernel_launch(void* const* d_in, const int* in_sizes, int n_in,
                              void* d_out, int out_size, void* d_ws, size_t ws_size,
                              hipStream_t stream) {
    const float4* feats4 = (const float4*)d_in[0];
    const int*    bidx   = (const int*)d_in[1];
    const float*  W1     = (const float*)d_in[2];
    const float*  b1     = (const float*)d_in[3];
    const float*  W2     = (const float*)d_in[4];
    const float*  b2     = (const float*)d_in[5];
    float4* out4 = (float4*)d_out;
    const int n_rows = in_sizes[1];
    const int n4     = n_rows * (CH / 4);

    // ws layout: sums[1024] | gate[1024] | partials[SEG_BLOCKS*1024]
    float* sums = (float*)d_ws;
    float* gate = sums + NBATCH * CH;
    const size_t need = (size_t)(2 * NBATCH * CH + SEG_BLOCKS * NBATCH * CH) * sizeof(float);
    // fallback: stash partials in d_out (read by reduce_kernel strictly
    // before apply_kernel overwrites d_out — stream-ordered)
    float* partials = (ws_size >= need) ? (gate + NBATCH * CH) : (float*)d_out;

    (void)hipMemsetAsync(sums, 0, NBATCH * CH * sizeof(float), stream);

    seg_partial_kernel<<<SEG_BLOCKS, SEG_THREADS, 0, stream>>>(
        feats4, bidx, partials, n_rows);

    reduce_kernel<<<RED_BLOCKS, 256, 0, stream>>>(
        (const float4*)partials, sums);

    mlp_kernel<<<1, 1024, 0, stream>>>(
        sums, bidx, n_rows, W1, b1, W2, b2, gate);

    apply_kernel<<<SEG_BLOCKS, SEG_THREADS, 0, stream>>>(
        feats4, bidx, (const float4*)gate, out4, n4);
}